// Round 8
// baseline (69.709 us; speedup 1.0000x reference)
//
#include <hip/hip_runtime.h>
#include <math.h>

// Problem constants (from reference)
#define NB 32      // batch
#define NN 8192    // neighbors
#define DD 384     // feature dim
#define LL 128     // latent dim
#define CHUNKS 32  // blocks per batch in stream kernel
#define RPB 256    // rows per block (NN/CHUNKS)
#define NWAVES 4   // waves per block
#define RPW 64     // rows per wave

// ---------------------------------------------------------------------------
// Kernel A: per-batch q = target@Wq+bq (internal), then u = scale*(Wk@q),
// c = scale*(bk.q). Wk is L2-warmed during the q matvec; u uses a dual-row
// half-wave butterfly. Block 0 probes the mask dtype encoding.
// ---------------------------------------------------------------------------
__global__ __launch_bounds__(384) void ga_prep(
    const float* __restrict__ target,
    const float* __restrict__ Wq, const float* __restrict__ bq,
    const float* __restrict__ Wk, const float* __restrict__ bk,
    const void* __restrict__ mask,
    float* __restrict__ u, float* __restrict__ c, int* __restrict__ flag)
{
    const int b = blockIdx.x;   // 32 blocks
    const int t = threadIdx.x;  // 384 threads
    const int w = t >> 6;       // wave 0..5
    const int l = t & 63;       // lane

    __shared__ float tgt[DD];
    __shared__ __align__(16) float qs[LL];
    __shared__ float qp[3][LL];
    __shared__ int s_notint, s_notflt;

    if (b == 0 && t == 0) { s_notint = 0; s_notflt = 0; }
    tgt[t] = target[b * DD + t];

    // Warm Wk into this XCD's L2 while q is being computed.
    {
        float wsum = 0.f;
#pragma unroll
        for (int k = 0; k < 8; ++k) wsum += Wk[t * 16 + k * 6144];
        asm volatile("" :: "v"(wsum));
    }
    __syncthreads();

    // Mask dtype probe (block 0 only): int32 {0,1} vs float32 vs bytes
    if (b == 0 && t < 256) {
        unsigned v = ((const unsigned*)mask)[t];
        if (v > 1u) s_notint = 1;                       // benign race, all write 1
        if (v != 0u && v != 0x3F800000u) s_notflt = 1;
    }

    // q[ll] = bq[ll] + sum_d tgt[d]*Wq[d*128+ll], split d into 3 segments
    const int ll = t & (LL - 1);
    const int seg = t >> 7;  // 0..2
    float acc = 0.f;
#pragma unroll 4
    for (int i = 0; i < 128; ++i) {
        int d = seg * 128 + i;
        acc += tgt[d] * Wq[d * LL + ll];  // coalesced across ll
    }
    qp[seg][ll] = acc;
    __syncthreads();
    if (t < LL) qs[t] = qp[0][t] + qp[1][t] + qp[2][t] + bq[t];
    __syncthreads();

    const float scale = 0.051031036307982884f;  // 1/sqrt(384)

    // c[b] = scale * dot(bk, qs): wave 0, lane-parallel float2 + butterfly
    if (w == 0) {
        const float2 bk2 = *(const float2*)&bk[2 * l];
        const float2 q2  = *(const float2*)&qs[2 * l];
        float part = bk2.x * q2.x + bk2.y * q2.y;
#pragma unroll
        for (int off = 32; off; off >>= 1) part += __shfl_xor(part, off, 64);
        if (l == 0) c[b] = part * scale;
    }

    // u[d] = scale * (Wk[d,:] . qs). Wave w owns rows [w*64, w*64+64).
    // Half-wave: lanes 0..31 row d, lanes 32..63 row d+1; 5-level reduce.
    {
        const int hw = l >> 5;      // 0 or 1
        const int j  = l & 31;      // 0..31
        const float4 q4 = *(const float4*)&qs[4 * j];
        for (int k = 0; k < 64; k += 4) {
            const int rowk = w * 64 + k;
            const int dA = rowk + hw;
            const int dB = rowk + 2 + hw;
            const float4 wkA = *(const float4*)&Wk[dA * LL + 4 * j];
            const float4 wkB = *(const float4*)&Wk[dB * LL + 4 * j];
            float pA = wkA.x * q4.x + wkA.y * q4.y + wkA.z * q4.z + wkA.w * q4.w;
            float pB = wkB.x * q4.x + wkB.y * q4.y + wkB.z * q4.z + wkB.w * q4.w;
#pragma unroll
            for (int off = 16; off; off >>= 1) {
                pA += __shfl_xor(pA, off, 64);
                pB += __shfl_xor(pB, off, 64);
            }
            if (j == 0) {   // lanes 0 and 32
                u[b * DD + dA] = pA * scale;
                u[b * DD + dB] = pB * scale;
            }
        }
    }

    __syncthreads();
    if (b == 0 && t == 0) *flag = s_notint ? (s_notflt ? 2 : 1) : 0;
}

// ---------------------------------------------------------------------------
// Kernel B: stream h (mask-skip) with a 3-DEEP register pipeline (A/B/C,
// 4-row stages, statically unrolled): while one stage computes, two stages
// (~192 cache lines/wave) are in flight. Online softmax, 384-wide
// accumulator. At block end, warm a 4KB slice of {Wv,W1,W2} into L2.
// ---------------------------------------------------------------------------

#define GA_LOAD4(Xa, Xb, B2) do {                                        \
    _Pragma("unroll")                                                    \
    for (int j = 0; j < 4; ++j) {                                        \
        const int rr = ((B2) + j < cnt) ? wlist[wave][(B2) + j] : 0;     \
        const float* rp = hb + (size_t)rr * DD;                          \
        Xa[j] = *(const float4*)(rp + 4 * lane);                         \
        Xb[j] = *(const float2*)(rp + 256 + 2 * lane);                   \
    } } while (0)

#define GA_COMP4(Xa, Xb, B2) do {                                        \
    float dd[4];                                                         \
    _Pragma("unroll")                                                    \
    for (int j = 0; j < 4; ++j)                                          \
        dd[j] = Xa[j].x * ua.x + Xa[j].y * ua.y + Xa[j].z * ua.z +       \
                Xa[j].w * ua.w + Xb[j].x * ub2.x + Xb[j].y * ub2.y;      \
    _Pragma("unroll")                                                    \
    for (int off = 32; off; off >>= 1) {                                 \
        _Pragma("unroll")                                                \
        for (int j = 0; j < 4; ++j) dd[j] += __shfl_xor(dd[j], off, 64); \
    }                                                                    \
    const int nv = cnt - (B2);                                           \
    float sv[4];                                                         \
    _Pragma("unroll")                                                    \
    for (int j = 0; j < 4; ++j)                                          \
        sv[j] = (j < nv) ? dd[j] + cc : -INFINITY;                       \
    float M4 = fmaxf(fmaxf(sv[0], sv[1]), fmaxf(sv[2], sv[3]));          \
    const float mn = fmaxf(m, M4);                                       \
    const float f = __expf(m - mn);  /* first stage: exp(-inf)=0 */      \
    m = mn;                                                              \
    s *= f;                                                              \
    a0 *= f; a1 *= f; a2 *= f; a3 *= f; a4 *= f; a5 *= f;                \
    float pp[4];                                                         \
    _Pragma("unroll")                                                    \
    for (int j = 0; j < 4; ++j)                                          \
        pp[j] = (j < nv) ? __expf(sv[j] - m) : 0.f;                      \
    s += (pp[0] + pp[1]) + (pp[2] + pp[3]);                              \
    _Pragma("unroll")                                                    \
    for (int j = 0; j < 4; ++j) {                                        \
        a0 += pp[j] * Xa[j].x; a1 += pp[j] * Xa[j].y;                    \
        a2 += pp[j] * Xa[j].z; a3 += pp[j] * Xa[j].w;                    \
        a4 += pp[j] * Xb[j].x; a5 += pp[j] * Xb[j].y;                    \
    } } while (0)

__global__ __launch_bounds__(256, 4) void ga_stream(
    const float* __restrict__ h, const void* __restrict__ mask,
    const float* __restrict__ u, const float* __restrict__ c,
    const int* __restrict__ flag,
    float* __restrict__ pm, float* __restrict__ ps, float* __restrict__ pa,
    const float* __restrict__ Wv, const float* __restrict__ W1,
    const float* __restrict__ W2)
{
    const int blk = blockIdx.x;           // 1024 blocks
    const int b = blk >> 5;               // batch
    const int chunk = blk & (CHUNKS - 1);
    const int wave = threadIdx.x >> 6;
    const int lane = threadIdx.x & 63;
    const int t = threadIdx.x;

    // u fragment: float4 over elems [0,256), float2 over [256,384)
    const float* ubase = u + b * DD;
    const float4 ua  = *(const float4*)(ubase + 4 * lane);
    const float2 ub2 = *(const float2*)(ubase + 256 + 2 * lane);
    const float cc = c[b];

    const int n0 = chunk * RPB + wave * RPW;
    const size_t rowbase = (size_t)b * NN + n0;
    const float* hb = h + rowbase * DD;

    // Gather this wave's 64 mask bits -> ballot, compact indices into LDS
    const int fm = *flag;
    int myMask;
    const size_t mi = rowbase + lane;
    if (fm == 0)      myMask = ((const int*)mask)[mi] != 0;
    else if (fm == 1) myMask = ((const unsigned*)mask)[mi] != 0u;
    else              myMask = ((const unsigned char*)mask)[mi] != 0;
    const unsigned long long mbits = __ballot(myMask);
    const int cnt = __popcll(mbits);
    const int pos = __popcll(mbits & ((1ull << lane) - 1ull));

    __shared__ int wlist[NWAVES][64];
    __shared__ float lm[NWAVES], lss[NWAVES];
    __shared__ float la[NWAVES][DD];

    if (myMask) wlist[wave][pos] = lane;   // wave-synchronous, no barrier needed

    float m = -INFINITY, s = 0.f;
    float a0 = 0.f, a1 = 0.f, a2 = 0.f, a3 = 0.f, a4 = 0.f, a5 = 0.f;

    float4 Axa[4]; float2 Axb[4];
    float4 Bxa[4]; float2 Bxb[4];
    float4 Cxa[4]; float2 Cxb[4];

    if (cnt > 0) {
        GA_LOAD4(Axa, Axb, 0);
        if (4 < cnt) GA_LOAD4(Bxa, Bxb, 4);
        int base = 0;
        while (true) {
            if (base + 8 < cnt) GA_LOAD4(Cxa, Cxb, base + 8);   // prefetch +2
            GA_COMP4(Axa, Axb, base);
            base += 4;
            if (base >= cnt) break;

            if (base + 8 < cnt) GA_LOAD4(Axa, Axb, base + 8);   // prefetch +2
            GA_COMP4(Bxa, Bxb, base);
            base += 4;
            if (base >= cnt) break;

            if (base + 8 < cnt) GA_LOAD4(Bxa, Bxb, base + 8);   // prefetch +2
            GA_COMP4(Cxa, Cxb, base);
            base += 4;
            if (base >= cnt) break;
        }
    }

    // ---- L2-warm a 4KB slice of {Wv|W1|W2} for ga_finish.
    __builtin_amdgcn_sched_barrier(0);
    {
        const int slice = (blk >> 3) & 127;
        const int idx = slice * 1024 + t * 4;   // float index into 128K-float concat
        const float* p = (idx < 49152) ? (Wv + idx)
                       : (idx < 114688) ? (W1 + (idx - 49152))
                                        : (W2 + (idx - 114688));
        const float4 wv4 = *(const float4*)p;
        asm volatile("" :: "v"(wv4.x), "v"(wv4.y), "v"(wv4.z), "v"(wv4.w));
    }

    // Accumulator layout: a0..a3 = elems 4*lane+{0..3}; a4,a5 = 256+2*lane+{0,1}
    *(float4*)&la[wave][4 * lane] = make_float4(a0, a1, a2, a3);
    *(float2*)&la[wave][256 + 2 * lane] = make_float2(a4, a5);
    if (lane == 0) { lm[wave] = m; lss[wave] = s; }
    __syncthreads();

    const float M = fmaxf(fmaxf(lm[0], lm[1]), fmaxf(lm[2], lm[3]));
    const float w0 = (lm[0] == -INFINITY) ? 0.f : __expf(lm[0] - M);
    const float w1 = (lm[1] == -INFINITY) ? 0.f : __expf(lm[1] - M);
    const float w2 = (lm[2] == -INFINITY) ? 0.f : __expf(lm[2] - M);
    const float w3 = (lm[3] == -INFINITY) ? 0.f : __expf(lm[3] - M);
    const float S = w0 * lss[0] + w1 * lss[1] + w2 * lss[2] + w3 * lss[3];
    if (t == 0) { pm[blk] = M; ps[blk] = S; }
    for (int idx = t; idx < DD; idx += 256) {
        pa[(size_t)blk * DD + idx] =
            w0 * la[0][idx] + w1 * la[1][idx] + w2 * la[2][idx] + w3 * la[3][idx];
    }
}

// ---------------------------------------------------------------------------
// Kernel C: per batch, reduce 32 partials -> a_norm[384]; nws = a_norm@Wv+bv;
// z=[nws,target]; out = relu(z@W1+b1)@W2+b2. 512 threads; every matvec is
// 4-way j-segmented with 4 independent accumulators.
// ---------------------------------------------------------------------------
__global__ __launch_bounds__(512) void ga_finish(
    const float* __restrict__ target,
    const float* __restrict__ Wv, const float* __restrict__ bv,
    const float* __restrict__ W1, const float* __restrict__ b1,
    const float* __restrict__ W2, const float* __restrict__ b2,
    const float* __restrict__ pm, const float* __restrict__ ps,
    const float* __restrict__ pa, float* __restrict__ out)
{
    const int b = blockIdx.x;   // 32 blocks
    const int t = threadIdx.x;  // 512 threads
    const int l = t & (LL - 1);
    const int seg = t >> 7;     // 0..3

    __shared__ float wg[CHUNKS];
    __shared__ float an[DD];
    __shared__ float z[LL + DD];   // 512
    __shared__ float hp[4][LL];
    __shared__ float hid[LL];

    float M = -INFINITY;
#pragma unroll
    for (int i = 0; i < CHUNKS; ++i) M = fmaxf(M, pm[b * CHUNKS + i]);
    if (t < CHUNKS) {
        const float mi = pm[b * CHUNKS + t];
        wg[t] = (mi == -INFINITY) ? 0.f : __expf(mi - M);
    }
    __syncthreads();

    float S = 0.f;
#pragma unroll
    for (int i = 0; i < CHUNKS; ++i) S += wg[i] * ps[b * CHUNKS + i];
    const float invS = 1.f / S;

    if (t < DD) {
        float v0 = 0.f, v1 = 0.f, v2 = 0.f, v3 = 0.f;
#pragma unroll
        for (int i = 0; i < CHUNKS; i += 4) {
            v0 += wg[i]     * pa[(size_t)(b * CHUNKS + i)     * DD + t];
            v1 += wg[i + 1] * pa[(size_t)(b * CHUNKS + i + 1) * DD + t];
            v2 += wg[i + 2] * pa[(size_t)(b * CHUNKS + i + 2) * DD + t];
            v3 += wg[i + 3] * pa[(size_t)(b * CHUNKS + i + 3) * DD + t];
        }
        an[t] = ((v0 + v1) + (v2 + v3)) * invS;
        z[LL + t] = target[b * DD + t];
    }
    __syncthreads();

    // nws[l] = bv[l] + sum_d an[d]*Wv[d*128+l]; 4 segments x 96 d's
    {
        const int start = seg * 96;
        float v0 = 0.f, v1 = 0.f, v2 = 0.f, v3 = 0.f;
#pragma unroll 2
        for (int k = 0; k < 96; k += 4) {
            const int d = start + k;
            v0 += an[d]     * Wv[(d)     * LL + l];
            v1 += an[d + 1] * Wv[(d + 1) * LL + l];
            v2 += an[d + 2] * Wv[(d + 2) * LL + l];
            v3 += an[d + 3] * Wv[(d + 3) * LL + l];
        }
        hp[seg][l] = (v0 + v1) + (v2 + v3);
    }
    __syncthreads();
    if (t < LL) z[t] = (hp[0][t] + hp[1][t]) + (hp[2][t] + hp[3][t]) + bv[t];
    __syncthreads();

    // hid[l] = relu(b1[l] + sum_j z[j]*W1[j*128+l]); 4 segments x 128 j's
    {
        const int start = seg * 128;
        float v0 = 0.f, v1 = 0.f, v2 = 0.f, v3 = 0.f;
#pragma unroll 2
        for (int k = 0; k < 128; k += 4) {
            const int j = start + k;
            v0 += z[j]     * W1[(j)     * LL + l];
            v1 += z[j + 1] * W1[(j + 1) * LL + l];
            v2 += z[j + 2] * W1[(j + 2) * LL + l];
            v3 += z[j + 3] * W1[(j + 3) * LL + l];
        }
        hp[seg][l] = (v0 + v1) + (v2 + v3);
    }
    __syncthreads();
    if (t < LL)
        hid[t] = fmaxf((hp[0][t] + hp[1][t]) + (hp[2][t] + hp[3][t]) + b1[t], 0.f);
    __syncthreads();

    // out[l] = b2[l] + sum_j hid[j]*W2[j*128+l]; 4 segments x 32 j's
    {
        const int start = seg * 32;
        float v0 = 0.f, v1 = 0.f, v2 = 0.f, v3 = 0.f;
#pragma unroll
        for (int k = 0; k < 32; k += 4) {
            const int j = start + k;
            v0 += hid[j]     * W2[(j)     * LL + l];
            v1 += hid[j + 1] * W2[(j + 1) * LL + l];
            v2 += hid[j + 2] * W2[(j + 2) * LL + l];
            v3 += hid[j + 3] * W2[(j + 3) * LL + l];
        }
        hp[seg][l] = (v0 + v1) + (v2 + v3);
    }
    __syncthreads();
    if (t < LL)
        out[b * LL + t] = (hp[0][t] + hp[1][t]) + (hp[2][t] + hp[3][t]) + b2[t];
}

// ---------------------------------------------------------------------------
extern "C" void kernel_launch(void* const* d_in, const int* in_sizes, int n_in,
                              void* d_out, int out_size, void* d_ws, size_t ws_size,
                              hipStream_t stream)
{
    const float* target = (const float*)d_in[0];
    const float* h      = (const float*)d_in[1];
    const void*  mask   = d_in[2];
    const float* Wq = (const float*)d_in[3];
    const float* bq = (const float*)d_in[4];
    const float* Wk = (const float*)d_in[5];
    const float* bk = (const float*)d_in[6];
    const float* Wv = (const float*)d_in[7];
    const float* bv = (const float*)d_in[8];
    const float* W1 = (const float*)d_in[9];
    const float* b1 = (const float*)d_in[10];
    const float* W2 = (const float*)d_in[11];
    const float* b2 = (const float*)d_in[12];
    float* out = (float*)d_out;

    float* ws = (float*)d_ws;
    int*   flag = (int*)d_ws;
    float* u  = ws + 64;                  // 32*384
    float* c  = u + NB * DD;              // 32
    float* pm = c + NB;                   // 1024
    float* ps = pm + NB * CHUNKS;         // 1024
    float* pa = ps + NB * CHUNKS;         // 1024*384

    hipLaunchKernelGGL(ga_prep, dim3(NB), dim3(DD), 0, stream,
                       target, Wq, bq, Wk, bk, mask, u, c, flag);
    hipLaunchKernelGGL(ga_stream, dim3(NB * CHUNKS), dim3(256), 0, stream,
                       h, mask, u, c, flag, pm, ps, pa, Wv, W1, W2);
    hipLaunchKernelGGL(ga_finish, dim3(NB), dim3(512), 0, stream,
                       target, Wv, bv, W1, b1, W2, b2, pm, ps, pa, out);
}

// Round 9
// 68.122 us; speedup vs baseline: 1.0233x; 1.0233x over previous
//
#include <hip/hip_runtime.h>
#include <math.h>

// Problem constants (from reference)
#define NB 32      // batch
#define NN 8192    // neighbors
#define DD 384     // feature dim
#define LL 128     // latent dim
#define CHUNKS 32  // blocks per batch in stream kernel
#define RPB 256    // rows per block (NN/CHUNKS)
#define NWAVES 4   // waves per block
#define RPW 64     // rows per wave

// ---------------------------------------------------------------------------
// Kernel A: per-batch q = target@Wq+bq (internal), then u = scale*(Wk@q),
// c = scale*(bk.q). Wk is L2-warmed during the q matvec; u uses a dual-row
// half-wave butterfly. Block 0 probes the mask dtype encoding.  (frozen r7)
// ---------------------------------------------------------------------------
__global__ __launch_bounds__(384) void ga_prep(
    const float* __restrict__ target,
    const float* __restrict__ Wq, const float* __restrict__ bq,
    const float* __restrict__ Wk, const float* __restrict__ bk,
    const void* __restrict__ mask,
    float* __restrict__ u, float* __restrict__ c, int* __restrict__ flag)
{
    const int b = blockIdx.x;   // 32 blocks
    const int t = threadIdx.x;  // 384 threads
    const int w = t >> 6;       // wave 0..5
    const int l = t & 63;       // lane

    __shared__ float tgt[DD];
    __shared__ __align__(16) float qs[LL];
    __shared__ float qp[3][LL];
    __shared__ int s_notint, s_notflt;

    if (b == 0 && t == 0) { s_notint = 0; s_notflt = 0; }
    tgt[t] = target[b * DD + t];

    // Warm Wk into this XCD's L2 while q is being computed.
    {
        float wsum = 0.f;
#pragma unroll
        for (int k = 0; k < 8; ++k) wsum += Wk[t * 16 + k * 6144];
        asm volatile("" :: "v"(wsum));
    }
    __syncthreads();

    // Mask dtype probe (block 0 only): int32 {0,1} vs float32 vs bytes
    if (b == 0 && t < 256) {
        unsigned v = ((const unsigned*)mask)[t];
        if (v > 1u) s_notint = 1;                       // benign race, all write 1
        if (v != 0u && v != 0x3F800000u) s_notflt = 1;
    }

    // q[ll] = bq[ll] + sum_d tgt[d]*Wq[d*128+ll], split d into 3 segments
    const int ll = t & (LL - 1);
    const int seg = t >> 7;  // 0..2
    float acc = 0.f;
#pragma unroll 4
    for (int i = 0; i < 128; ++i) {
        int d = seg * 128 + i;
        acc += tgt[d] * Wq[d * LL + ll];  // coalesced across ll
    }
    qp[seg][ll] = acc;
    __syncthreads();
    if (t < LL) qs[t] = qp[0][t] + qp[1][t] + qp[2][t] + bq[t];
    __syncthreads();

    const float scale = 0.051031036307982884f;  // 1/sqrt(384)

    // c[b] = scale * dot(bk, qs): wave 0, lane-parallel float2 + butterfly
    if (w == 0) {
        const float2 bk2 = *(const float2*)&bk[2 * l];
        const float2 q2  = *(const float2*)&qs[2 * l];
        float part = bk2.x * q2.x + bk2.y * q2.y;
#pragma unroll
        for (int off = 32; off; off >>= 1) part += __shfl_xor(part, off, 64);
        if (l == 0) c[b] = part * scale;
    }

    // u[d] = scale * (Wk[d,:] . qs). Wave w owns rows [w*64, w*64+64).
    {
        const int hw = l >> 5;      // 0 or 1
        const int j  = l & 31;      // 0..31
        const float4 q4 = *(const float4*)&qs[4 * j];
        for (int k = 0; k < 64; k += 4) {
            const int rowk = w * 64 + k;
            const int dA = rowk + hw;
            const int dB = rowk + 2 + hw;
            const float4 wkA = *(const float4*)&Wk[dA * LL + 4 * j];
            const float4 wkB = *(const float4*)&Wk[dB * LL + 4 * j];
            float pA = wkA.x * q4.x + wkA.y * q4.y + wkA.z * q4.z + wkA.w * q4.w;
            float pB = wkB.x * q4.x + wkB.y * q4.y + wkB.z * q4.z + wkB.w * q4.w;
#pragma unroll
            for (int off = 16; off; off >>= 1) {
                pA += __shfl_xor(pA, off, 64);
                pB += __shfl_xor(pB, off, 64);
            }
            if (j == 0) {   // lanes 0 and 32
                u[b * DD + dA] = pA * scale;
                u[b * DD + dB] = pB * scale;
            }
        }
    }

    __syncthreads();
    if (b == 0 && t == 0) *flag = s_notint ? (s_notflt ? 2 : 1) : 0;
}

// ---------------------------------------------------------------------------
// Kernel B: stream h (mask-skip) with a BLOCK-WIDE WORK POOL: all 256 row
// indices compacted into one LDS list (ballot counts + prefix offsets);
// the 4 waves consume interleaved 4-row groups (wave w: groups w, w+4, ...),
// so per-wave work is cnt/4 +-1 group instead of Binomial(64,.5) tails.
// 2-deep register ping-pong prefetch. Online softmax, 384-wide accumulator.
// At block end, warm a 4KB slice of {Wv,W1,W2} into L2 for ga_finish.
// ---------------------------------------------------------------------------

#define GA_LOAD4(Xa, Xb, B2) do {                                        \
    _Pragma("unroll")                                                    \
    for (int j = 0; j < 4; ++j) {                                        \
        const int rr = ((B2) + j < cnt) ? rlist[(B2) + j] : 0;           \
        const float* rp = hb + (size_t)rr * DD;                          \
        Xa[j] = *(const float4*)(rp + 4 * lane);                         \
        Xb[j] = *(const float2*)(rp + 256 + 2 * lane);                   \
    } } while (0)

#define GA_COMP4(Xa, Xb, B2) do {                                        \
    float dd[4];                                                         \
    _Pragma("unroll")                                                    \
    for (int j = 0; j < 4; ++j)                                          \
        dd[j] = Xa[j].x * ua.x + Xa[j].y * ua.y + Xa[j].z * ua.z +       \
                Xa[j].w * ua.w + Xb[j].x * ub2.x + Xb[j].y * ub2.y;      \
    _Pragma("unroll")                                                    \
    for (int off = 32; off; off >>= 1) {                                 \
        _Pragma("unroll")                                                \
        for (int j = 0; j < 4; ++j) dd[j] += __shfl_xor(dd[j], off, 64); \
    }                                                                    \
    const int nv = cnt - (B2);                                           \
    float sv[4];                                                         \
    _Pragma("unroll")                                                    \
    for (int j = 0; j < 4; ++j)                                          \
        sv[j] = (j < nv) ? dd[j] + cc : -INFINITY;                       \
    float M4 = fmaxf(fmaxf(sv[0], sv[1]), fmaxf(sv[2], sv[3]));          \
    const float mn = fmaxf(m, M4);                                       \
    const float f = __expf(m - mn);  /* first stage: exp(-inf)=0 */      \
    m = mn;                                                              \
    s *= f;                                                              \
    a0 *= f; a1 *= f; a2 *= f; a3 *= f; a4 *= f; a5 *= f;                \
    float pp[4];                                                         \
    _Pragma("unroll")                                                    \
    for (int j = 0; j < 4; ++j)                                          \
        pp[j] = (j < nv) ? __expf(sv[j] - m) : 0.f;                      \
    s += (pp[0] + pp[1]) + (pp[2] + pp[3]);                              \
    _Pragma("unroll")                                                    \
    for (int j = 0; j < 4; ++j) {                                        \
        a0 += pp[j] * Xa[j].x; a1 += pp[j] * Xa[j].y;                    \
        a2 += pp[j] * Xa[j].z; a3 += pp[j] * Xa[j].w;                    \
        a4 += pp[j] * Xb[j].x; a5 += pp[j] * Xb[j].y;                    \
    } } while (0)

__global__ __launch_bounds__(256, 4) void ga_stream(
    const float* __restrict__ h, const void* __restrict__ mask,
    const float* __restrict__ u, const float* __restrict__ c,
    const int* __restrict__ flag,
    float* __restrict__ pm, float* __restrict__ ps, float* __restrict__ pa,
    const float* __restrict__ Wv, const float* __restrict__ W1,
    const float* __restrict__ W2)
{
    const int blk = blockIdx.x;           // 1024 blocks
    const int b = blk >> 5;               // batch
    const int chunk = blk & (CHUNKS - 1);
    const int wave = threadIdx.x >> 6;
    const int lane = threadIdx.x & 63;
    const int t = threadIdx.x;

    // u fragment: float4 over elems [0,256), float2 over [256,384)
    const float* ubase = u + b * DD;
    const float4 ua  = *(const float4*)(ubase + 4 * lane);
    const float2 ub2 = *(const float2*)(ubase + 256 + 2 * lane);
    const float cc = c[b];

    // Block's 256-row window
    const size_t rowbase0 = (size_t)b * NN + chunk * RPB;
    const float* hb = h + rowbase0 * DD;

    // Gather this wave's 64 mask bits; build the block-wide compacted list
    const int fm = *flag;
    int myMask;
    const size_t mi = rowbase0 + wave * RPW + lane;
    if (fm == 0)      myMask = ((const int*)mask)[mi] != 0;
    else if (fm == 1) myMask = ((const unsigned*)mask)[mi] != 0u;
    else              myMask = ((const unsigned char*)mask)[mi] != 0;
    const unsigned long long mbits = __ballot(myMask);
    const int wcnt_mine = __popcll(mbits);
    const int pos = __popcll(mbits & ((1ull << lane) - 1ull));

    __shared__ int wcnt[NWAVES];
    __shared__ int rlist[RPB];
    __shared__ float lm[NWAVES], lss[NWAVES];
    __shared__ float la[NWAVES][DD];

    if (lane == 0) wcnt[wave] = wcnt_mine;
    __syncthreads();

    int off = 0;
#pragma unroll
    for (int i = 0; i < NWAVES; ++i) if (i < wave) off += wcnt[i];
    const int cnt = wcnt[0] + wcnt[1] + wcnt[2] + wcnt[3];
    if (myMask) rlist[off + pos] = wave * RPW + lane;
    __syncthreads();

    float m = -INFINITY, s = 0.f;
    float a0 = 0.f, a1 = 0.f, a2 = 0.f, a3 = 0.f, a4 = 0.f, a5 = 0.f;

    float4 Axa[4]; float2 Axb[4];
    float4 Bxa[4]; float2 Bxb[4];

    // Wave w consumes 4-row groups at base = 4*(w + 4k): w, w+4, w+8, ...
    {
        int base = wave * 4;
        if (base < cnt) {
            GA_LOAD4(Axa, Axb, base);
            int nb = base + 16;
            while (true) {
                if (nb < cnt) GA_LOAD4(Bxa, Bxb, nb);   // prefetch next group
                GA_COMP4(Axa, Axb, base);
                base = nb; nb += 16;
                if (base >= cnt) break;
                if (nb < cnt) GA_LOAD4(Axa, Axb, nb);   // prefetch next group
                GA_COMP4(Bxa, Bxb, base);
                base = nb; nb += 16;
                if (base >= cnt) break;
            }
        }
    }

    // ---- L2-warm a 4KB slice of {Wv|W1|W2} for ga_finish.
    __builtin_amdgcn_sched_barrier(0);
    {
        const int slice = (blk >> 3) & 127;
        const int idx = slice * 1024 + t * 4;   // float index into 128K-float concat
        const float* p = (idx < 49152) ? (Wv + idx)
                       : (idx < 114688) ? (W1 + (idx - 49152))
                                        : (W2 + (idx - 114688));
        const float4 wv4 = *(const float4*)p;
        asm volatile("" :: "v"(wv4.x), "v"(wv4.y), "v"(wv4.z), "v"(wv4.w));
    }

    // Accumulator layout: a0..a3 = elems 4*lane+{0..3}; a4,a5 = 256+2*lane+{0,1}
    *(float4*)&la[wave][4 * lane] = make_float4(a0, a1, a2, a3);
    *(float2*)&la[wave][256 + 2 * lane] = make_float2(a4, a5);
    if (lane == 0) { lm[wave] = m; lss[wave] = s; }
    __syncthreads();

    const float M = fmaxf(fmaxf(lm[0], lm[1]), fmaxf(lm[2], lm[3]));
    const float w0 = (lm[0] == -INFINITY) ? 0.f : __expf(lm[0] - M);
    const float w1 = (lm[1] == -INFINITY) ? 0.f : __expf(lm[1] - M);
    const float w2 = (lm[2] == -INFINITY) ? 0.f : __expf(lm[2] - M);
    const float w3 = (lm[3] == -INFINITY) ? 0.f : __expf(lm[3] - M);
    const float S = w0 * lss[0] + w1 * lss[1] + w2 * lss[2] + w3 * lss[3];
    if (t == 0) { pm[blk] = M; ps[blk] = S; }
    for (int idx = t; idx < DD; idx += 256) {
        pa[(size_t)blk * DD + idx] =
            w0 * la[0][idx] + w1 * la[1][idx] + w2 * la[2][idx] + w3 * la[3][idx];
    }
}

// ---------------------------------------------------------------------------
// Kernel C: per batch, reduce 32 partials -> a_norm[384]; nws = a_norm@Wv+bv;
// z=[nws,target]; out = relu(z@W1+b1)@W2+b2. 512 threads; every matvec is
// 4-way j-segmented with 4 independent accumulators.  (frozen r7)
// ---------------------------------------------------------------------------
__global__ __launch_bounds__(512) void ga_finish(
    const float* __restrict__ target,
    const float* __restrict__ Wv, const float* __restrict__ bv,
    const float* __restrict__ W1, const float* __restrict__ b1,
    const float* __restrict__ W2, const float* __restrict__ b2,
    const float* __restrict__ pm, const float* __restrict__ ps,
    const float* __restrict__ pa, float* __restrict__ out)
{
    const int b = blockIdx.x;   // 32 blocks
    const int t = threadIdx.x;  // 512 threads
    const int l = t & (LL - 1);
    const int seg = t >> 7;     // 0..3

    __shared__ float wg[CHUNKS];
    __shared__ float an[DD];
    __shared__ float z[LL + DD];   // 512
    __shared__ float hp[4][LL];
    __shared__ float hid[LL];

    float M = -INFINITY;
#pragma unroll
    for (int i = 0; i < CHUNKS; ++i) M = fmaxf(M, pm[b * CHUNKS + i]);
    if (t < CHUNKS) {
        const float mi = pm[b * CHUNKS + t];
        wg[t] = (mi == -INFINITY) ? 0.f : __expf(mi - M);
    }
    __syncthreads();

    float S = 0.f;
#pragma unroll
    for (int i = 0; i < CHUNKS; ++i) S += wg[i] * ps[b * CHUNKS + i];
    const float invS = 1.f / S;

    if (t < DD) {
        float v0 = 0.f, v1 = 0.f, v2 = 0.f, v3 = 0.f;
#pragma unroll
        for (int i = 0; i < CHUNKS; i += 4) {
            v0 += wg[i]     * pa[(size_t)(b * CHUNKS + i)     * DD + t];
            v1 += wg[i + 1] * pa[(size_t)(b * CHUNKS + i + 1) * DD + t];
            v2 += wg[i + 2] * pa[(size_t)(b * CHUNKS + i + 2) * DD + t];
            v3 += wg[i + 3] * pa[(size_t)(b * CHUNKS + i + 3) * DD + t];
        }
        an[t] = ((v0 + v1) + (v2 + v3)) * invS;
        z[LL + t] = target[b * DD + t];
    }
    __syncthreads();

    // nws[l] = bv[l] + sum_d an[d]*Wv[d*128+l]; 4 segments x 96 d's
    {
        const int start = seg * 96;
        float v0 = 0.f, v1 = 0.f, v2 = 0.f, v3 = 0.f;
#pragma unroll 2
        for (int k = 0; k < 96; k += 4) {
            const int d = start + k;
            v0 += an[d]     * Wv[(d)     * LL + l];
            v1 += an[d + 1] * Wv[(d + 1) * LL + l];
            v2 += an[d + 2] * Wv[(d + 2) * LL + l];
            v3 += an[d + 3] * Wv[(d + 3) * LL + l];
        }
        hp[seg][l] = (v0 + v1) + (v2 + v3);
    }
    __syncthreads();
    if (t < LL) z[t] = (hp[0][t] + hp[1][t]) + (hp[2][t] + hp[3][t]) + bv[t];
    __syncthreads();

    // hid[l] = relu(b1[l] + sum_j z[j]*W1[j*128+l]); 4 segments x 128 j's
    {
        const int start = seg * 128;
        float v0 = 0.f, v1 = 0.f, v2 = 0.f, v3 = 0.f;
#pragma unroll 2
        for (int k = 0; k < 128; k += 4) {
            const int j = start + k;
            v0 += z[j]     * W1[(j)     * LL + l];
            v1 += z[j + 1] * W1[(j + 1) * LL + l];
            v2 += z[j + 2] * W1[(j + 2) * LL + l];
            v3 += z[j + 3] * W1[(j + 3) * LL + l];
        }
        hp[seg][l] = (v0 + v1) + (v2 + v3);
    }
    __syncthreads();
    if (t < LL)
        hid[t] = fmaxf((hp[0][t] + hp[1][t]) + (hp[2][t] + hp[3][t]) + b1[t], 0.f);
    __syncthreads();

    // out[l] = b2[l] + sum_j hid[j]*W2[j*128+l]; 4 segments x 32 j's
    {
        const int start = seg * 32;
        float v0 = 0.f, v1 = 0.f, v2 = 0.f, v3 = 0.f;
#pragma unroll
        for (int k = 0; k < 32; k += 4) {
            const int j = start + k;
            v0 += hid[j]     * W2[(j)     * LL + l];
            v1 += hid[j + 1] * W2[(j + 1) * LL + l];
            v2 += hid[j + 2] * W2[(j + 2) * LL + l];
            v3 += hid[j + 3] * W2[(j + 3) * LL + l];
        }
        hp[seg][l] = (v0 + v1) + (v2 + v3);
    }
    __syncthreads();
    if (t < LL)
        out[b * LL + t] = (hp[0][t] + hp[1][t]) + (hp[2][t] + hp[3][t]) + b2[t];
}

// ---------------------------------------------------------------------------
extern "C" void kernel_launch(void* const* d_in, const int* in_sizes, int n_in,
                              void* d_out, int out_size, void* d_ws, size_t ws_size,
                              hipStream_t stream)
{
    const float* target = (const float*)d_in[0];
    const float* h      = (const float*)d_in[1];
    const void*  mask   = d_in[2];
    const float* Wq = (const float*)d_in[3];
    const float* bq = (const float*)d_in[4];
    const float* Wk = (const float*)d_in[5];
    const float* bk = (const float*)d_in[6];
    const float* Wv = (const float*)d_in[7];
    const float* bv = (const float*)d_in[8];
    const float* W1 = (const float*)d_in[9];
    const float* b1 = (const float*)d_in[10];
    const float* W2 = (const float*)d_in[11];
    const float* b2 = (const float*)d_in[12];
    float* out = (float*)d_out;

    float* ws = (float*)d_ws;
    int*   flag = (int*)d_ws;
    float* u  = ws + 64;                  // 32*384
    float* c  = u + NB * DD;              // 32
    float* pm = c + NB;                   // 1024
    float* ps = pm + NB * CHUNKS;         // 1024
    float* pa = ps + NB * CHUNKS;         // 1024*384

    hipLaunchKernelGGL(ga_prep, dim3(NB), dim3(DD), 0, stream,
                       target, Wq, bq, Wk, bk, mask, u, c, flag);
    hipLaunchKernelGGL(ga_stream, dim3(NB * CHUNKS), dim3(256), 0, stream,
                       h, mask, u, c, flag, pm, ps, pa, Wv, W1, W2);
    hipLaunchKernelGGL(ga_finish, dim3(NB), dim3(512), 0, stream,
                       target, Wv, bv, W1, b1, W2, b2, pm, ps, pa, out);
}